// Round 4
// baseline (1017.476 us; speedup 1.0000x reference)
//
#include <hip/hip_runtime.h>
#include <math.h>

#define NB 16
#define NSY 180
#define NSX 360
#define NCIN 16
#define NW 32
#define NMODES 32
#define NPIX (NSY*NSX)     // 64800
#define NPTS (NB*NPIX)     // 1036800

typedef unsigned int uint;
typedef unsigned short ushort;
typedef __attribute__((ext_vector_type(8))) short bf16x8;
typedef __attribute__((ext_vector_type(4))) float f32x4;

union U4 { uint u[4]; bf16x8 v; };

// tanh-gelu with fast rcp: v*sigmoid(1.5957691*(v+0.044715 v^3))
__device__ __forceinline__ float gelu_f(float v){
  float u = v*(-1.5957691216f - 0.0713548163f*v*v);
  return v * __builtin_amdgcn_rcpf(1.f + __expf(u));
}
__device__ __forceinline__ ushort f2bf(float x){
  uint u = __float_as_uint(x);
  return (ushort)((u + 0x7FFFu + ((u>>16)&1u)) >> 16);
}
__device__ __forceinline__ uint packbf2(float a, float b){
  return (uint)f2bf(a) | ((uint)f2bf(b) << 16);
}
__device__ __forceinline__ float bf2f(ushort u){
  return __uint_as_float(((uint)u) << 16);
}
__device__ __forceinline__ uint addbf2(uint h, uint a){
  return packbf2(bf2f((ushort)(h & 0xffffu)) + bf2f((ushort)(a & 0xffffu)),
                 bf2f((ushort)(h >> 16))     + bf2f((ushort)(a >> 16)));
}

// ---------------- prep: bf16 Vandermonde (zero-padded), grid, fc1^T, w2 bf16 ----------------
__global__ __launch_bounds__(256) void k_prep(const float* __restrict__ sx,
    const float* __restrict__ sy, const float* __restrict__ fc1_w,
    const float* __restrict__ w2m,
    ushort* __restrict__ Abfy, ushort* __restrict__ Abfx,
    ushort* __restrict__ VyCT, ushort* __restrict__ VxCT,
    ushort* __restrict__ f1Tbf, ushort* __restrict__ w2bf,
    float* __restrict__ gx, float* __restrict__ gy){
  int idx = blockIdx.x*256 + threadIdx.x;
  float sx0 = sx[0], sxL = sx[NSX-1];
  float sy0 = sy[0], syL = sy[NSY-1];
  const float scy = 0.07453559924999298980f;   // 1/sqrt(180)
  const float scx = 0.05270462766947298886f;   // 1/sqrt(360)
  if (idx < NSX) gx[idx] = (sx[idx]-sx0)/sxL;
  if (idx < NSY) gy[idx] = (sy[idx]-sy0)/syL;
  if (idx < 64*192){
    int kri = idx/192, m = idx%192;
    float val = 0.f;
    if (m < NSY){
      int k = kri>>1;
      float p = (sy[m]-sy0)/(syL-sy0);
      float ang = -6.2831853071795864769f*(float)k*p;
      val = ((kri&1)? sinf(ang) : cosf(ang))*scy;
    }
    Abfy[idx] = f2bf(val);
  }
  if (idx < 192*64){
    int m = idx/64, kri = idx%64;
    float val = 0.f;
    if (m < NSY){
      int k = kri>>1;
      float p = (sy[m]-sy0)/(syL-sy0);
      float ang = -6.2831853071795864769f*(float)k*p;
      val = ((kri&1)? sinf(ang) : cosf(ang))*scy;
    }
    VyCT[idx] = f2bf(val);
  }
  if (idx < 64*384){
    int kri = idx/384, n = idx%384;
    float val = 0.f;
    if (n < NSX){
      int k = kri>>1;
      float p = (sx[n]-sx0)/(sxL-sx0);
      float ang = -6.2831853071795864769f*(float)k*p;
      val = ((kri&1)? sinf(ang) : cosf(ang))*scx;
    }
    Abfx[idx] = f2bf(val);
  }
  if (idx < 384*64){
    int n = idx/64, kri = idx%64;
    float val = 0.f;
    if (n < NSX){
      int k = kri>>1;
      float p = (sx[n]-sx0)/(sxL-sx0);
      float ang = -6.2831853071795864769f*(float)k*p;
      val = ((kri&1)? sinf(ang) : cosf(ang))*scx;
    }
    VxCT[idx] = f2bf(val);
  }
  if (idx < 128*32){
    int j = idx >> 5, c = idx & 31;
    f1Tbf[idx] = f2bf(fc1_w[c*128 + j]);
  }
  if (idx < 4096){
    // w2m: [4][o=32][c=32] fp32 -> bf16, same layout (B-frag reads [o][c])
    w2bf[idx] = f2bf(w2m[idx]);
  }
}

// ---------------- fold pointwise w1 into the mode-mix weights (fp32) ----------------
__global__ __launch_bounds__(256) void k_fold(const float* __restrict__ fw1,
    const float* __restrict__ fw2, const float* __restrict__ w1m,
    float* __restrict__ w1f, float* __restrict__ w2f){
  int id = blockIdx.x*256 + threadIdx.x;      // 0..262143
  int half = id >> 17;
  int r = id & 131071;
  int i  = r >> 15;
  int in = (r >> 10) & 31;
  int k  = (r >> 5) & 31;
  int o  = r & 31;
  const float* src = half ? fw2 : fw1;
  const float* wm  = w1m + i*1024 + o*32;
  const float* sp  = src + ((size_t)((i*32+in)*1024 + k))*2;
  float sR = 0.f, sI = 0.f;
  #pragma unroll
  for (int c=0;c<32;c++){
    float w = wm[c];
    sR += w * sp[c*64];
    sI += w * sp[c*64+1];
  }
  float* dst = half ? w2f : w1f;
  size_t oi = ((size_t)((i*32+in)*32 + k)*32 + o)*2;
  dst[oi] = sR; dst[oi+1] = sI;
}

// ---------------- fc0 -> hbf (bf16 residual stream) ----------------
__global__ __launch_bounds__(256) void k_fc0(const float* __restrict__ x,
    const float* __restrict__ gx, const float* __restrict__ gy,
    const float* __restrict__ fw, const float* __restrict__ fb,
    ushort* __restrict__ hbf){
  int p = blockIdx.x*256 + threadIdx.x;
  if (p >= NPTS) return;
  int b = p/NPIX, r = p%NPIX, m = r/NSX, n = r%NSX;
  const float* xp = x + (size_t)p*NCIN;
  float xv[NCIN+2];
  #pragma unroll
  for (int j=0;j<NCIN;j++) xv[j] = xp[j];
  xv[16] = gx[n]; xv[17] = gy[m];
  float acc[NW];
  #pragma unroll
  for (int o=0;o<NW;o++) acc[o] = fb[o];
  #pragma unroll
  for (int j=0;j<NCIN+2;j++){
    float v = xv[j];
    #pragma unroll
    for (int o=0;o<NW;o++) acc[o] += v*fw[j*32+o];
  }
  ushort* hq = hbf + (size_t)b*NW*NPIX + r;
  #pragma unroll
  for (int o=0;o<NW;o++) hq[(size_t)o*NPIX] = f2bf(acc[o]);
}

// ---------------- merged MFMA forward DFTs (y + x in one dispatch) ----------------
// v3: cooperative fat-load staging. y: 1 uint4/thread/step (8 rows x 128B per
// wave instr) -> raw LDS tile -> conflict-free repack -> Bt. x: lane remap so
// 4 threads/row (16 rows x 64B per wave instr) -> Bt direct. Depth-2 register
// prefetch on the global streams; double-buffered LDS.
__global__ __launch_bounds__(256) void k_fwd(const ushort* __restrict__ hbf,
    const ushort* __restrict__ Abfy, const ushort* __restrict__ Abfx,
    uint* __restrict__ fty, uint* __restrict__ ftx, int b0, int ylim){
  __shared__ ushort rawS[2][32*64];   // 2 x 4KB raw tile (y-branch)
  __shared__ uint   BtS[2][64*18];    // 2 x 4.6KB packed B
  int bx = blockIdx.x;
  int tid = threadIdx.x;
  int l = tid & 63, g = tid >> 6;
  int c15 = l & 15, q = l >> 4;
  if (bx < ylim){
    int nt6 = bx % 6; int c = (bx/6) & 31; int bb = bx/192;
    int n0 = nt6*64;
    const ushort* hb = hbf + (size_t)((b0+bb)*NW + c)*NPIX;
    // cooperative tile load mapping: row r = tid>>3 (0..31), col chunk (tid&7)*8
    int yr = tid >> 3, yc = (tid & 7) << 3;
    auto ldY = [&](int ks)->uint4{
      int m = ks*32 + yr;
      int gc = n0 + yc;
      uint4 p = {0u,0u,0u,0u};
      if (m < NSY && gc < NSX) p = *(const uint4*)(hb + (size_t)m*NSX + gc);
      return p;
    };
    bf16x8 afr[6];
    #pragma unroll
    for (int ks=0; ks<6; ks++)
      afr[ks] = *(const bf16x8*)(Abfy + (size_t)(16*g + c15)*192 + ks*32 + q*8);
    f32x4 acc[4];
    #pragma unroll
    for (int t=0;t<4;t++) acc[t] = (f32x4){0.f,0.f,0.f,0.f};
    uint4 pre0 = ldY(0);
    uint4 pre1 = ldY(1);
    #pragma unroll
    for (int ks=0; ks<6; ks++){
      // commit prefetched tile -> raw LDS (contiguous 16B/thread)
      uint4 cur = (ks&1) ? pre1 : pre0;
      *(uint4*)(&rawS[ks&1][(size_t)tid*8]) = cur;
      __syncthreads();                 // raw[ks&1] ready
      if (ks < 4){
        if (ks&1) pre1 = ldY(ks+2); else pre0 = ldY(ks+2);
      }
      // repack: column l gather (same-dword broadcast reads, conflict-free)
      const ushort* rp = rawS[ks&1];
      ushort v[8];
      #pragma unroll
      for (int j=0;j<8;j++) v[j] = rp[(8*g + j)*64 + l];
      #pragma unroll
      for (int i=0;i<4;i++)
        BtS[ks&1][l*18 + 4*g + i] = (uint)v[2*i] | ((uint)v[2*i+1] << 16);
      __syncthreads();                 // Bt[ks&1] ready
      #pragma unroll
      for (int nt=0; nt<4; nt++){
        const uint* bp = &BtS[ks&1][(nt*16 + c15)*18 + q*4];
        U4 bu;
        uint2 lo = *(const uint2*)(bp);
        uint2 hi = *(const uint2*)(bp+2);
        bu.u[0]=lo.x; bu.u[1]=lo.y; bu.u[2]=hi.x; bu.u[3]=hi.y;
        acc[nt] = __builtin_amdgcn_mfma_f32_16x16x32_bf16(afr[ks], bu.v, acc[nt], 0,0,0);
      }
    }
    uint* fb = fty + (size_t)(bb*NW + c)*32*NSX;
    int k0 = 8*g + 2*q;
    #pragma unroll
    for (int nt=0; nt<4; nt++){
      int nn = n0 + nt*16 + c15;
      if (nn < NSX){
        fb[(size_t)k0*NSX + nn]     = packbf2(acc[nt][0], acc[nt][1]);
        fb[(size_t)(k0+1)*NSX + nn] = packbf2(acc[nt][2], acc[nt][3]);
      }
    }
  } else {
    int t = bx - ylim;
    int mt = t % 3; int c = (t/3) & 31; int bb = t/96;
    int m0 = mt*64;
    const ushort* hb = hbf + (size_t)((b0+bb)*NW + c)*NPIX;
    // cooperative mapping: row r = tid>>2 (0..63), n chunk (tid&3)*8
    int xr = tid >> 2, xc = (tid & 3) << 3;
    auto ldX = [&](int ks)->uint4{
      int m = m0 + xr;
      int n = ks*32 + xc;
      uint4 p = {0u,0u,0u,0u};
      if (m < NSY && n < NSX) p = *(const uint4*)(hb + (size_t)m*NSX + n);
      return p;
    };
    auto ldA = [&](int ks)->bf16x8{
      return *(const bf16x8*)(Abfx + (size_t)(16*g + c15)*384 + ks*32 + q*8);
    };
    f32x4 acc[4];
    #pragma unroll
    for (int tt=0;tt<4;tt++) acc[tt] = (f32x4){0.f,0.f,0.f,0.f};
    uint4 pre0 = ldX(0), pre1 = ldX(1);
    bf16x8 a0 = ldA(0), a1 = ldA(1);
    int s4 = (tid & 3) * 4;
    #pragma unroll
    for (int ks=0; ks<12; ks++){
      uint4 cur = (ks&1) ? pre1 : pre0;
      bf16x8 af = (ks&1) ? a1 : a0;
      uint* btp = &BtS[ks&1][xr*18 + s4];
      btp[0] = cur.x; btp[1] = cur.y; btp[2] = cur.z; btp[3] = cur.w;
      if (ks < 10){
        if (ks&1){ pre1 = ldX(ks+2); a1 = ldA(ks+2); }
        else     { pre0 = ldX(ks+2); a0 = ldA(ks+2); }
      }
      __syncthreads();                 // Bt[ks&1] ready
      #pragma unroll
      for (int nt=0; nt<4; nt++){
        const uint* bp = &BtS[ks&1][(nt*16 + c15)*18 + q*4];
        U4 bu;
        uint2 lo = *(const uint2*)(bp);
        uint2 hi = *(const uint2*)(bp+2);
        bu.u[0]=lo.x; bu.u[1]=lo.y; bu.u[2]=hi.x; bu.u[3]=hi.y;
        acc[nt] = __builtin_amdgcn_mfma_f32_16x16x32_bf16(af, bu.v, acc[nt], 0,0,0);
      }
    }
    uint* fb = ftx + (size_t)(bb*NW + c)*32*NSY;
    int k0 = 8*g + 2*q;
    #pragma unroll
    for (int nt=0; nt<4; nt++){
      int mm = m0 + nt*16 + c15;
      if (mm < NSY){
        fb[(size_t)k0*NSY + mm]     = packbf2(acc[nt][0], acc[nt][1]);
        fb[(size_t)(k0+1)*NSY + mm] = packbf2(acc[nt][2], acc[nt][3]);
      }
    }
  }
}

// ---------------- unified per-mode complex channel mix (y + x in one dispatch) ----------------
__global__ __launch_bounds__(192) void k_mix(const uint* __restrict__ fty,
    const uint* __restrict__ ftx, const float* __restrict__ w1f,
    const float* __restrict__ w2f, uint* __restrict__ oy, uint* __restrict__ ox,
    int ylim){
  int bx = blockIdx.x;
  const uint* ft; const float* wf; uint* oo; int Nlen, k, bb, n;
  if (bx < ylim){
    int t = bx; int nt = t & 1; k = (t>>1) & 31; bb = t >> 6;
    n = nt*192 + threadIdx.x; ft = fty; wf = w1f; oo = oy; Nlen = NSX;
  } else {
    int t = bx - ylim; k = t & 31; bb = t >> 5;
    n = threadIdx.x; ft = ftx; wf = w2f; oo = ox; Nlen = NSY;
  }
  bool valid = n < Nlen;
  int nn = valid ? n : (Nlen-1);
  const uint* fb = ft + ((size_t)(bb*NW)*32 + k)*Nlen + nn;
  const float* wb = wf + (size_t)k*64;
  float aR[32], aI[32];
  #pragma unroll
  for (int o=0;o<32;o++){ aR[o]=0.f; aI[o]=0.f; }
  for (int in=0; in<32; in++){
    uint f = fb[(size_t)in*32*Nlen];
    float fR = bf2f((ushort)(f & 0xffffu));
    float fI = bf2f((ushort)(f >> 16));
    const float* wrow = wb + in*2048;
    #pragma unroll
    for (int o=0;o<32;o++){
      float wR = wrow[o*2], wI = wrow[o*2+1];
      aR[o] += fR*wR - fI*wI;
      aI[o] += fR*wI + fI*wR;
    }
  }
  if (valid){
    uint* ob = oo + ((size_t)(bb*NW)*32 + k)*Nlen + n;
    #pragma unroll
    for (int o=0;o<32;o++){
      ob[(size_t)o*32*Nlen] = packbf2(aR[o], aI[o]);
    }
  }
}

// ---------------- MFMA inverse (y+x combined), full-M blocks, XCD-swizzled ----------------
// One block per (bb, o, n-tile of 64). Stages ALL m of ox once (At) + oy slice (Bt).
// Wave g computes m-tiles 3g..3g+2 x 4 n-tiles, K=128 in 4 steps.
// v2 epilogue: gelu in fp32, then LDS transpose (reusing At, stride 36 uints so
// rows are 16B-aligned) -> coalesced uint4 stores (8 lanes x 16B per row),
// replacing 48 scalar ushort stores/thread with 6 uint4 stores/thread.
__global__ __launch_bounds__(256) void k_inv(const uint* __restrict__ oyb,
    const uint* __restrict__ oxb, const ushort* __restrict__ VyCT,
    const ushort* __restrict__ VxCT, const float* __restrict__ b1,
    ushort* __restrict__ x2bf){
  __shared__ uint At[192*34];   // [m][k] 26.1 KB (reused as 180x36-uint out tile)
  __shared__ uint Bt[64*34];    // [n][k]  8.7 KB
  int bx = blockIdx.x;
  // swizzle: 6 blocks of one (bb,o) share an XCD (assumes round-robin bx%8->XCD)
  int c8 = bx & 7; int rr = bx >> 3; int slot = rr/6; int nt6 = rr - slot*6;
  int gid = slot*8 + c8;
  int bb = gid >> 5; int o = gid & 31;
  int n0 = nt6*64;
  int tid = threadIdx.x;
  int l = tid & 63, g = tid >> 6;
  int c15 = l & 15, q = l >> 4;
  const uint* oxp = oxb + (size_t)(bb*NW + o)*32*NSY;
  const uint* oyp = oyb + (size_t)(bb*NW + o)*32*NSX;
  #pragma unroll
  for (int i=0;i<24;i++){
    int idx = tid + i*256;          // < 6144
    int k = idx/192, m = idx - k*192;
    At[m*34 + k] = (m < NSY) ? oxp[(size_t)k*NSY + m] : 0u;
  }
  #pragma unroll
  for (int i=0;i<8;i++){
    int idx = tid + i*256;          // < 2048
    int k = idx >> 6, n = idx & 63;
    int ng = n0 + n;
    Bt[n*34 + k] = (ng < NSX) ? oyp[(size_t)k*NSX + ng] : 0u;
  }
  __syncthreads();
  f32x4 acc[3][4];
  #pragma unroll
  for (int mt=0;mt<3;mt++)
    #pragma unroll
    for (int nt=0;nt<4;nt++) acc[mt][nt] = (f32x4){0.f,0.f,0.f,0.f};
  #pragma unroll
  for (int s=0;s<4;s++){
    bf16x8 bfr[4];
    #pragma unroll
    for (int nt=0;nt<4;nt++){
      if (s < 2){
        const uint* bp = &Bt[(nt*16 + c15)*34 + s*16 + q*4];
        U4 bu; uint2 lo = *(const uint2*)bp; uint2 hi = *(const uint2*)(bp+2);
        bu.u[0]=lo.x; bu.u[1]=lo.y; bu.u[2]=hi.x; bu.u[3]=hi.y;
        bfr[nt] = bu.v;
      } else {
        bfr[nt] = *(const bf16x8*)(VxCT + (size_t)(n0 + nt*16 + c15)*64 + (s-2)*32 + q*8);
      }
    }
    #pragma unroll
    for (int mt=0;mt<3;mt++){
      int mrow = g*48 + mt*16 + c15;
      bf16x8 afr;
      if (s < 2){
        afr = *(const bf16x8*)(VyCT + (size_t)mrow*64 + s*32 + q*8);
      } else {
        const uint* ap = &At[mrow*34 + (s-2)*16 + q*4];
        U4 au; uint2 lo = *(const uint2*)ap; uint2 hi = *(const uint2*)(ap+2);
        au.u[0]=lo.x; au.u[1]=lo.y; au.u[2]=hi.x; au.u[3]=hi.y;
        afr = au.v;
      }
      #pragma unroll
      for (int nt=0;nt<4;nt++)
        acc[mt][nt] = __builtin_amdgcn_mfma_f32_16x16x32_bf16(afr, bfr[nt], acc[mt][nt], 0,0,0);
    }
  }
  // ---- epilogue: gelu -> LDS tile (reuse At; [180 m][36 uint] rows) -> fat stores ----
  __syncthreads();                       // all At reads done
  float bias = b1[o];
  ushort* Ous = (ushort*)At;             // row stride 72 ushorts (36 uints, 144B: 16B-aligned)
  #pragma unroll
  for (int mt=0;mt<3;mt++){
    int nlB = 0;
    #pragma unroll
    for (int nt=0;nt<4;nt++){
      int nl = nt*16 + c15;
      #pragma unroll
      for (int r2=0;r2<4;r2++){
        int m = g*48 + mt*16 + q*4 + r2;
        if (m < NSY) Ous[m*72 + nl] = f2bf(gelu_f(acc[mt][nt][r2] + bias));
      }
    }
    (void)nlB;
  }
  __syncthreads();
  uint* x2u = (uint*)(x2bf + (size_t)(bb*NW + o)*NPIX);
  int row8 = tid >> 3, ch = tid & 7;
  int halfn0 = n0 >> 1;
  int maxu = (NSX/2 - halfn0) < 32 ? (NSX/2 - halfn0) : 32;   // uints in this tile's row
  #pragma unroll
  for (int p=0;p<6;p++){
    int m = p*32 + row8;
    if (m < NSY && (ch*4 + 4) <= maxu){
      const uint* lp = At + m*36 + ch*4;
      uint4 v; v.x = lp[0]; v.y = lp[1]; v.z = lp[2]; v.w = lp[3];
      *(uint4*)(x2u + (size_t)m*(NSX/2) + halfn0 + ch*4) = v;
    }
  }
}

// ---------------- MFMA pointwise: hbf += (gelu?)(W2 @ x2g + b2) ----------------
// x2bf already holds gelu(x1+b1) (bf16, planar [bb][c][NPIX]).
// Block = 256 px of one bb; wave g: pixels g*64..g*64+63 (4 m-tiles x 2 n-tiles MFMA).
// Epilogue transposes through LDS so the hbf RMW is coalesced per-channel rows.
__global__ __launch_bounds__(256) void k_pw2(const ushort* __restrict__ x2bf,
    const ushort* __restrict__ w2b, const float* __restrict__ b2,
    uint* __restrict__ hbfu, int last, int b0, int nloc){
  const int HP = NPIX/2;            // 32400
  __shared__ uint Ot[32*132];       // [o][px2], stride 132 (16B-aligned rows, bank-spread)
  int blk = blockIdx.x;
  int bb = blk/254, bt = blk - bb*254;
  int pxb = bt*256;
  int tid = threadIdx.x;
  int g = tid >> 6, l = tid & 63;
  int c15 = l & 15, q = l >> 4;
  // B fragments: W2 bf16, [o][c]; col o = nt*16+c15, k = q*8+j
  bf16x8 bfr[2];
  #pragma unroll
  for (int nt=0; nt<2; nt++)
    bfr[nt] = *(const bf16x8*)(w2b + (size_t)(nt*16 + c15)*32 + q*8);
  // A fragments (gelu'd x2) + MFMA
  const ushort* xb = x2bf + ((size_t)bb*NW + q*8)*NPIX;
  f32x4 acc[4][2];
  #pragma unroll
  for (int mt=0;mt<4;mt++){
    U4 au; au.u[0]=0u; au.u[1]=0u; au.u[2]=0u; au.u[3]=0u;
    int pr = pxb + g*64 + mt*16 + c15;
    if (pr < NPIX){
      ushort v[8];
      #pragma unroll
      for (int j=0;j<8;j++) v[j] = xb[(size_t)j*NPIX + pr];
      #pragma unroll
      for (int i2=0;i2<4;i2++) au.u[i2] = (uint)v[2*i2] | ((uint)v[2*i2+1] << 16);
    }
    #pragma unroll
    for (int nt=0;nt<2;nt++){
      acc[mt][nt] = (f32x4){0.f,0.f,0.f,0.f};
      acc[mt][nt] = __builtin_amdgcn_mfma_f32_16x16x32_bf16(au.v, bfr[nt], acc[mt][nt], 0,0,0);
    }
  }
  // phase 1: bias + (gelu) -> LDS transpose [o][px2]
  #pragma unroll
  for (int nt=0;nt<2;nt++){
    int o = nt*16 + c15;
    float bias = b2[o];
    #pragma unroll
    for (int mt=0;mt<4;mt++){
      float v0 = acc[mt][nt][0] + bias;
      float v1 = acc[mt][nt][1] + bias;
      float v2 = acc[mt][nt][2] + bias;
      float v3 = acc[mt][nt][3] + bias;
      if (!last){ v0=gelu_f(v0); v1=gelu_f(v1); v2=gelu_f(v2); v3=gelu_f(v3); }
      int px2 = g*32 + mt*8 + q*2;            // (pixel within block)/2, even
      uint2 w2v; w2v.x = packbf2(v0,v1); w2v.y = packbf2(v2,v3);
      *(uint2*)(&Ot[o*132 + px2]) = w2v;
    }
  }
  __syncthreads();
  // phase 2: coalesced residual RMW on hbf; 8 threads per o-row, 16 uints each
  int o = tid >> 3, t8 = tid & 7;
  uint* hb = hbfu + ((size_t)((b0+bb)*NW + o))*HP + (pxb>>1) + t8*16;
  const uint* lrow = &Ot[o*132 + t8*16];
  int p2g0 = (pxb>>1) + t8*16;
  #pragma unroll
  for (int jj=0; jj<16; jj+=4){
    if (p2g0 + jj + 4 <= HP){
      uint4 hv = *(const uint4*)(hb + jj);
      uint4 av = *(const uint4*)(lrow + jj);
      uint4 r;
      r.x = addbf2(hv.x, av.x); r.y = addbf2(hv.y, av.y);
      r.z = addbf2(hv.z, av.z); r.w = addbf2(hv.w, av.w);
      *(uint4*)(hb + jj) = r;
    } else {
      #pragma unroll
      for (int t=0;t<4;t++){
        if (p2g0 + jj + t < HP){
          uint hv = hb[jj+t];
          hb[jj+t] = addbf2(hv, lrow[jj+t]);
        }
      }
    }
  }
}

// ---------------- MFMA fc1 + gelu + fc2 (reads bf16 hbf planar) ----------------
__global__ __launch_bounds__(256) void k_fc12m(const ushort* __restrict__ hbf,
    const ushort* __restrict__ f1Tbf, const float* __restrict__ f1b,
    const float* __restrict__ f2w, const float* __restrict__ f2b,
    float* __restrict__ out){
  int blk = blockIdx.x; int tid = threadIdx.x;
  int g = tid >> 6, lane = tid & 63;
  int c15 = lane & 15, q = lane >> 4;
  int pbase = blk*64 + g*16;
  int pglob = pbase + c15;
  int b = pglob/NPIX, r = pglob%NPIX;
  const ushort* hb = hbf + (size_t)b*NW*NPIX + r;
  U4 au;
  #pragma unroll
  for (int i=0;i<4;i++){
    uint v0 = hb[(size_t)(q*8 + 2*i)*NPIX];
    uint v1 = hb[(size_t)(q*8 + 2*i + 1)*NPIX];
    au.u[i] = v0 | (v1 << 16);
  }
  bf16x8 afr = au.v;
  f32x4 acc[8];
  #pragma unroll
  for (int t=0;t<8;t++) acc[t] = (f32x4){0.f,0.f,0.f,0.f};
  #pragma unroll
  for (int nt=0; nt<8; nt++){
    bf16x8 bfr = *(const bf16x8*)(f1Tbf + (size_t)(nt*16 + c15)*32 + q*8);
    acc[nt] = __builtin_amdgcn_mfma_f32_16x16x32_bf16(afr, bfr, acc[nt], 0,0,0);
  }
  float s[4] = {0.f,0.f,0.f,0.f};
  #pragma unroll
  for (int nt=0; nt<8; nt++){
    int j = nt*16 + c15;
    float bj = f1b[j], wj = f2w[j];
    #pragma unroll
    for (int r2=0;r2<4;r2++) s[r2] += gelu_f(acc[nt][r2] + bj) * wj;
  }
  #pragma unroll
  for (int msk=1; msk<16; msk<<=1){
    #pragma unroll
    for (int r2=0;r2<4;r2++) s[r2] += __shfl_xor(s[r2], msk, 64);
  }
  if (c15 == 0){
    float fb2 = f2b[0];
    float4 v = {s[0]+fb2, s[1]+fb2, s[2]+fb2, s[3]+fb2};
    *(float4*)(out + pbase + q*4) = v;
  }
}

extern "C" void kernel_launch(void* const* d_in, const int* in_sizes, int n_in,
                              void* d_out, int out_size, void* d_ws, size_t ws_size,
                              hipStream_t stream) {
  const float* x     = (const float*)d_in[0];
  const float* sx    = (const float*)d_in[1];
  const float* sy    = (const float*)d_in[2];
  const float* fc0_w = (const float*)d_in[3];
  const float* fc0_b = (const float*)d_in[4];
  const float* fw1   = (const float*)d_in[5];
  const float* fw2   = (const float*)d_in[6];
  const float* w1m   = (const float*)d_in[7];
  const float* b1    = (const float*)d_in[8];
  const float* w2m   = (const float*)d_in[9];
  const float* b2    = (const float*)d_in[10];
  const float* fc1_w = (const float*)d_in[11];
  const float* fc1_b = (const float*)d_in[12];
  const float* fc2_w = (const float*)d_in[13];
  const float* fc2_b = (const float*)d_in[14];
  float* out = (float*)d_out;

  char* wsb = (char*)d_ws;
  size_t off = 0;
  auto alloc = [&](size_t bytes)->char*{
    char* p = wsb + off;
    off = (off + bytes + 255) & ~(size_t)255;
    return p;
  };
  ushort* hbf   = (ushort*)alloc((size_t)NB*NW*NPIX*2);    // 66.4 MB (residual stream)
  ushort* Abfy  = (ushort*)alloc(64*192*2);
  ushort* Abfx  = (ushort*)alloc(64*384*2);
  ushort* VyCT  = (ushort*)alloc(192*64*2);
  ushort* VxCT  = (ushort*)alloc(384*64*2);
  ushort* f1Tbf = (ushort*)alloc(128*32*2);
  ushort* w2bf  = (ushort*)alloc(4096*2);
  float*  gx    = (float*)alloc(NSX*4);
  float*  gy    = (float*)alloc(NSY*4);
  float*  w1f   = (float*)alloc(262144*4);
  float*  w2f   = (float*)alloc(262144*4);
  const size_t fixedB = off;

  // per-batch: x2bf (4,147,200 B) ALIASES [fty | ftx | pad] (ft dead after k_mix)
  const size_t szX2  = (size_t)NW*NPIX*2;
  const size_t szFty = (size_t)NW*32*NSX*4;
  const size_t szFtx = (size_t)NW*32*NSY*4;
  const size_t szOy  = szFty, szOx = szFtx;
  const size_t perB  = szX2 + szOy + szOx;      // 6,359,040 B

  int NC = 16;
  while (NC > 1 && fixedB + (size_t)NC*perB + 4096 > ws_size) NC >>= 1;
  char* pb = wsb + fixedB;
  ushort* x2bf = (ushort*)pb;
  uint*   fty  = (uint*)pb;                               // aliases x2bf head
  uint*   ftx  = (uint*)(pb + (size_t)NC*szFty);          // aliases x2bf tail
  uint*   oy   = (uint*)(pb + (size_t)NC*szX2);
  uint*   ox   = (uint*)((char*)oy + (size_t)NC*szOy);

  k_prep<<<96, 256, 0, stream>>>(sx, sy, fc1_w, w2m, Abfy, Abfx, VyCT, VxCT,
                                 f1Tbf, w2bf, gx, gy);
  k_fold<<<1024, 256, 0, stream>>>(fw1, fw2, w1m, w1f, w2f);
  k_fc0<<<4050, 256, 0, stream>>>(x, gx, gy, fc0_w, fc0_b, hbf);

  for (int i=0;i<4;i++){
    for (int b0=0; b0<NB; b0+=NC){
      k_fwd<<<NC*288, 256, 0, stream>>>(hbf, Abfy, Abfx, fty, ftx, b0, NC*192);
      k_mix<<<NC*96, 192, 0, stream>>>(fty, ftx, w1f + (size_t)i*65536,
                                       w2f + (size_t)i*65536, oy, ox, NC*64);
      k_inv<<<NC*192, 256, 0, stream>>>(oy, ox, VyCT, VxCT, b1 + i*32, x2bf);
      k_pw2<<<NC*254, 256, 0, stream>>>((const ushort*)x2bf,
                                        w2bf + (size_t)i*1024,
                                        b2 + i*32, (uint*)hbf,
                                        (int)(i==3), b0, NC);
    }
  }

  k_fc12m<<<NPTS/64, 256, 0, stream>>>(hbf, f1Tbf, fc1_b, fc2_w, fc2_b, out);
}

// Round 5
// 944.462 us; speedup vs baseline: 1.0773x; 1.0773x over previous
//
#include <hip/hip_runtime.h>
#include <math.h>

#define NB 16
#define NSY 180
#define NSX 360
#define NCIN 16
#define NW 32
#define NMODES 32
#define NPIX (NSY*NSX)     // 64800
#define NPTS (NB*NPIX)     // 1036800

typedef unsigned int uint;
typedef unsigned short ushort;
typedef __attribute__((ext_vector_type(8))) short bf16x8;
typedef __attribute__((ext_vector_type(4))) float f32x4;

union U4 { uint u[4]; bf16x8 v; };

// tanh-gelu with fast rcp: v*sigmoid(1.5957691*(v+0.044715 v^3))
__device__ __forceinline__ float gelu_f(float v){
  float u = v*(-1.5957691216f - 0.0713548163f*v*v);
  return v * __builtin_amdgcn_rcpf(1.f + __expf(u));
}
__device__ __forceinline__ ushort f2bf(float x){
  uint u = __float_as_uint(x);
  return (ushort)((u + 0x7FFFu + ((u>>16)&1u)) >> 16);
}
__device__ __forceinline__ uint packbf2(float a, float b){
  return (uint)f2bf(a) | ((uint)f2bf(b) << 16);
}
__device__ __forceinline__ float bf2f(ushort u){
  return __uint_as_float(((uint)u) << 16);
}
__device__ __forceinline__ uint addbf2(uint h, uint a){
  return packbf2(bf2f((ushort)(h & 0xffffu)) + bf2f((ushort)(a & 0xffffu)),
                 bf2f((ushort)(h >> 16))     + bf2f((ushort)(a >> 16)));
}

// ---------------- prep: bf16 Vandermonde (zero-padded), grid, fc1^T, w2 bf16 ----------------
__global__ __launch_bounds__(256) void k_prep(const float* __restrict__ sx,
    const float* __restrict__ sy, const float* __restrict__ fc1_w,
    const float* __restrict__ w2m,
    ushort* __restrict__ Abfy, ushort* __restrict__ Abfx,
    ushort* __restrict__ VyCT, ushort* __restrict__ VxCT,
    ushort* __restrict__ f1Tbf, ushort* __restrict__ w2bf,
    float* __restrict__ gx, float* __restrict__ gy){
  int idx = blockIdx.x*256 + threadIdx.x;
  float sx0 = sx[0], sxL = sx[NSX-1];
  float sy0 = sy[0], syL = sy[NSY-1];
  const float scy = 0.07453559924999298980f;   // 1/sqrt(180)
  const float scx = 0.05270462766947298886f;   // 1/sqrt(360)
  if (idx < NSX) gx[idx] = (sx[idx]-sx0)/sxL;
  if (idx < NSY) gy[idx] = (sy[idx]-sy0)/syL;
  if (idx < 64*192){
    int kri = idx/192, m = idx%192;
    float val = 0.f;
    if (m < NSY){
      int k = kri>>1;
      float p = (sy[m]-sy0)/(syL-sy0);
      float ang = -6.2831853071795864769f*(float)k*p;
      val = ((kri&1)? sinf(ang) : cosf(ang))*scy;
    }
    Abfy[idx] = f2bf(val);
  }
  if (idx < 192*64){
    int m = idx/64, kri = idx%64;
    float val = 0.f;
    if (m < NSY){
      int k = kri>>1;
      float p = (sy[m]-sy0)/(syL-sy0);
      float ang = -6.2831853071795864769f*(float)k*p;
      val = ((kri&1)? sinf(ang) : cosf(ang))*scy;
    }
    VyCT[idx] = f2bf(val);
  }
  if (idx < 64*384){
    int kri = idx/384, n = idx%384;
    float val = 0.f;
    if (n < NSX){
      int k = kri>>1;
      float p = (sx[n]-sx0)/(sxL-sx0);
      float ang = -6.2831853071795864769f*(float)k*p;
      val = ((kri&1)? sinf(ang) : cosf(ang))*scx;
    }
    Abfx[idx] = f2bf(val);
  }
  if (idx < 384*64){
    int n = idx/64, kri = idx%64;
    float val = 0.f;
    if (n < NSX){
      int k = kri>>1;
      float p = (sx[n]-sx0)/(sxL-sx0);
      float ang = -6.2831853071795864769f*(float)k*p;
      val = ((kri&1)? sinf(ang) : cosf(ang))*scx;
    }
    VxCT[idx] = f2bf(val);
  }
  if (idx < 128*32){
    int j = idx >> 5, c = idx & 31;
    f1Tbf[idx] = f2bf(fc1_w[c*128 + j]);
  }
  if (idx < 4096){
    // w2m: [4][o=32][c=32] fp32 -> bf16, same layout (B-frag reads [o][c])
    w2bf[idx] = f2bf(w2m[idx]);
  }
}

// ---------------- fold pointwise w1 into the mode-mix weights (fp32) ----------------
__global__ __launch_bounds__(256) void k_fold(const float* __restrict__ fw1,
    const float* __restrict__ fw2, const float* __restrict__ w1m,
    float* __restrict__ w1f, float* __restrict__ w2f){
  int id = blockIdx.x*256 + threadIdx.x;      // 0..262143
  int half = id >> 17;
  int r = id & 131071;
  int i  = r >> 15;
  int in = (r >> 10) & 31;
  int k  = (r >> 5) & 31;
  int o  = r & 31;
  const float* src = half ? fw2 : fw1;
  const float* wm  = w1m + i*1024 + o*32;
  const float* sp  = src + ((size_t)((i*32+in)*1024 + k))*2;
  float sR = 0.f, sI = 0.f;
  #pragma unroll
  for (int c=0;c<32;c++){
    float w = wm[c];
    sR += w * sp[c*64];
    sI += w * sp[c*64+1];
  }
  float* dst = half ? w2f : w1f;
  size_t oi = ((size_t)((i*32+in)*32 + k)*32 + o)*2;
  dst[oi] = sR; dst[oi+1] = sI;
}

// ---------------- fc0 -> hbf (bf16 residual stream) ----------------
__global__ __launch_bounds__(256) void k_fc0(const float* __restrict__ x,
    const float* __restrict__ gx, const float* __restrict__ gy,
    const float* __restrict__ fw, const float* __restrict__ fb,
    ushort* __restrict__ hbf){
  int p = blockIdx.x*256 + threadIdx.x;
  if (p >= NPTS) return;
  int b = p/NPIX, r = p%NPIX, m = r/NSX, n = r%NSX;
  const float* xp = x + (size_t)p*NCIN;
  float xv[NCIN+2];
  #pragma unroll
  for (int j=0;j<NCIN;j++) xv[j] = xp[j];
  xv[16] = gx[n]; xv[17] = gy[m];
  float acc[NW];
  #pragma unroll
  for (int o=0;o<NW;o++) acc[o] = fb[o];
  #pragma unroll
  for (int j=0;j<NCIN+2;j++){
    float v = xv[j];
    #pragma unroll
    for (int o=0;o<NW;o++) acc[o] += v*fw[j*32+o];
  }
  ushort* hq = hbf + (size_t)b*NW*NPIX + r;
  #pragma unroll
  for (int o=0;o<NW;o++) hq[(size_t)o*NPIX] = f2bf(acc[o]);
}

// ---------------- merged MFMA forward DFTs (y + x in one dispatch) ----------------
// v3: cooperative fat-load staging. y: 1 uint4/thread/step (8 rows x 128B per
// wave instr) -> raw LDS tile -> conflict-free repack -> Bt. x: lane remap so
// 4 threads/row (16 rows x 64B per wave instr) -> Bt direct. Depth-2 register
// prefetch on the global streams; double-buffered LDS.
__global__ __launch_bounds__(256) void k_fwd(const ushort* __restrict__ hbf,
    const ushort* __restrict__ Abfy, const ushort* __restrict__ Abfx,
    uint* __restrict__ fty, uint* __restrict__ ftx, int b0, int ylim){
  __shared__ ushort rawS[2][32*64];   // 2 x 4KB raw tile (y-branch)
  __shared__ uint   BtS[2][64*18];    // 2 x 4.6KB packed B
  int bx = blockIdx.x;
  int tid = threadIdx.x;
  int l = tid & 63, g = tid >> 6;
  int c15 = l & 15, q = l >> 4;
  if (bx < ylim){
    int nt6 = bx % 6; int c = (bx/6) & 31; int bb = bx/192;
    int n0 = nt6*64;
    const ushort* hb = hbf + (size_t)((b0+bb)*NW + c)*NPIX;
    // cooperative tile load mapping: row r = tid>>3 (0..31), col chunk (tid&7)*8
    int yr = tid >> 3, yc = (tid & 7) << 3;
    auto ldY = [&](int ks)->uint4{
      int m = ks*32 + yr;
      int gc = n0 + yc;
      uint4 p = {0u,0u,0u,0u};
      if (m < NSY && gc < NSX) p = *(const uint4*)(hb + (size_t)m*NSX + gc);
      return p;
    };
    bf16x8 afr[6];
    #pragma unroll
    for (int ks=0; ks<6; ks++)
      afr[ks] = *(const bf16x8*)(Abfy + (size_t)(16*g + c15)*192 + ks*32 + q*8);
    f32x4 acc[4];
    #pragma unroll
    for (int t=0;t<4;t++) acc[t] = (f32x4){0.f,0.f,0.f,0.f};
    uint4 pre0 = ldY(0);
    uint4 pre1 = ldY(1);
    #pragma unroll
    for (int ks=0; ks<6; ks++){
      // commit prefetched tile -> raw LDS (contiguous 16B/thread)
      uint4 cur = (ks&1) ? pre1 : pre0;
      *(uint4*)(&rawS[ks&1][(size_t)tid*8]) = cur;
      __syncthreads();                 // raw[ks&1] ready
      if (ks < 4){
        if (ks&1) pre1 = ldY(ks+2); else pre0 = ldY(ks+2);
      }
      // repack: column l gather (same-dword broadcast reads, conflict-free)
      const ushort* rp = rawS[ks&1];
      ushort v[8];
      #pragma unroll
      for (int j=0;j<8;j++) v[j] = rp[(8*g + j)*64 + l];
      #pragma unroll
      for (int i=0;i<4;i++)
        BtS[ks&1][l*18 + 4*g + i] = (uint)v[2*i] | ((uint)v[2*i+1] << 16);
      __syncthreads();                 // Bt[ks&1] ready
      #pragma unroll
      for (int nt=0; nt<4; nt++){
        const uint* bp = &BtS[ks&1][(nt*16 + c15)*18 + q*4];
        U4 bu;
        uint2 lo = *(const uint2*)(bp);
        uint2 hi = *(const uint2*)(bp+2);
        bu.u[0]=lo.x; bu.u[1]=lo.y; bu.u[2]=hi.x; bu.u[3]=hi.y;
        acc[nt] = __builtin_amdgcn_mfma_f32_16x16x32_bf16(afr[ks], bu.v, acc[nt], 0,0,0);
      }
    }
    uint* fb = fty + (size_t)(bb*NW + c)*32*NSX;
    int k0 = 8*g + 2*q;
    #pragma unroll
    for (int nt=0; nt<4; nt++){
      int nn = n0 + nt*16 + c15;
      if (nn < NSX){
        fb[(size_t)k0*NSX + nn]     = packbf2(acc[nt][0], acc[nt][1]);
        fb[(size_t)(k0+1)*NSX + nn] = packbf2(acc[nt][2], acc[nt][3]);
      }
    }
  } else {
    int t = bx - ylim;
    int mt = t % 3; int c = (t/3) & 31; int bb = t/96;
    int m0 = mt*64;
    const ushort* hb = hbf + (size_t)((b0+bb)*NW + c)*NPIX;
    // cooperative mapping: row r = tid>>2 (0..63), n chunk (tid&3)*8
    int xr = tid >> 2, xc = (tid & 3) << 3;
    auto ldX = [&](int ks)->uint4{
      int m = m0 + xr;
      int n = ks*32 + xc;
      uint4 p = {0u,0u,0u,0u};
      if (m < NSY && n < NSX) p = *(const uint4*)(hb + (size_t)m*NSX + n);
      return p;
    };
    auto ldA = [&](int ks)->bf16x8{
      return *(const bf16x8*)(Abfx + (size_t)(16*g + c15)*384 + ks*32 + q*8);
    };
    f32x4 acc[4];
    #pragma unroll
    for (int tt=0;tt<4;tt++) acc[tt] = (f32x4){0.f,0.f,0.f,0.f};
    uint4 pre0 = ldX(0), pre1 = ldX(1);
    bf16x8 a0 = ldA(0), a1 = ldA(1);
    int s4 = (tid & 3) * 4;
    #pragma unroll
    for (int ks=0; ks<12; ks++){
      uint4 cur = (ks&1) ? pre1 : pre0;
      bf16x8 af = (ks&1) ? a1 : a0;
      uint* btp = &BtS[ks&1][xr*18 + s4];
      btp[0] = cur.x; btp[1] = cur.y; btp[2] = cur.z; btp[3] = cur.w;
      if (ks < 10){
        if (ks&1){ pre1 = ldX(ks+2); a1 = ldA(ks+2); }
        else     { pre0 = ldX(ks+2); a0 = ldA(ks+2); }
      }
      __syncthreads();                 // Bt[ks&1] ready
      #pragma unroll
      for (int nt=0; nt<4; nt++){
        const uint* bp = &BtS[ks&1][(nt*16 + c15)*18 + q*4];
        U4 bu;
        uint2 lo = *(const uint2*)(bp);
        uint2 hi = *(const uint2*)(bp+2);
        bu.u[0]=lo.x; bu.u[1]=lo.y; bu.u[2]=hi.x; bu.u[3]=hi.y;
        acc[nt] = __builtin_amdgcn_mfma_f32_16x16x32_bf16(af, bu.v, acc[nt], 0,0,0);
      }
    }
    uint* fb = ftx + (size_t)(bb*NW + c)*32*NSY;
    int k0 = 8*g + 2*q;
    #pragma unroll
    for (int nt=0; nt<4; nt++){
      int mm = m0 + nt*16 + c15;
      if (mm < NSY){
        fb[(size_t)k0*NSY + mm]     = packbf2(acc[nt][0], acc[nt][1]);
        fb[(size_t)(k0+1)*NSY + mm] = packbf2(acc[nt][2], acc[nt][3]);
      }
    }
  }
}

// ---------------- unified per-mode complex channel mix (y + x in one dispatch) ----------------
__global__ __launch_bounds__(192) void k_mix(const uint* __restrict__ fty,
    const uint* __restrict__ ftx, const float* __restrict__ w1f,
    const float* __restrict__ w2f, uint* __restrict__ oy, uint* __restrict__ ox,
    int ylim){
  int bx = blockIdx.x;
  const uint* ft; const float* wf; uint* oo; int Nlen, k, bb, n;
  if (bx < ylim){
    int t = bx; int nt = t & 1; k = (t>>1) & 31; bb = t >> 6;
    n = nt*192 + threadIdx.x; ft = fty; wf = w1f; oo = oy; Nlen = NSX;
  } else {
    int t = bx - ylim; k = t & 31; bb = t >> 5;
    n = threadIdx.x; ft = ftx; wf = w2f; oo = ox; Nlen = NSY;
  }
  bool valid = n < Nlen;
  int nn = valid ? n : (Nlen-1);
  const uint* fb = ft + ((size_t)(bb*NW)*32 + k)*Nlen + nn;
  const float* wb = wf + (size_t)k*64;
  float aR[32], aI[32];
  #pragma unroll
  for (int o=0;o<32;o++){ aR[o]=0.f; aI[o]=0.f; }
  for (int in=0; in<32; in++){
    uint f = fb[(size_t)in*32*Nlen];
    float fR = bf2f((ushort)(f & 0xffffu));
    float fI = bf2f((ushort)(f >> 16));
    const float* wrow = wb + in*2048;
    #pragma unroll
    for (int o=0;o<32;o++){
      float wR = wrow[o*2], wI = wrow[o*2+1];
      aR[o] += fR*wR - fI*wI;
      aI[o] += fR*wI + fI*wR;
    }
  }
  if (valid){
    uint* ob = oo + ((size_t)(bb*NW)*32 + k)*Nlen + n;
    #pragma unroll
    for (int o=0;o<32;o++){
      ob[(size_t)o*32*Nlen] = packbf2(aR[o], aI[o]);
    }
  }
}

// ---------------- MFMA inverse (y+x combined), full-M blocks, XCD-swizzled ----------------
// v3: occupancy-first. At LDS staging REMOVED — the x-part A fragments are
// gathered directly from global ox (4 dword loads per (mt,s); lanes give 16
// consecutive m = 64B segments, L2-resident). LDS is now only Bt (8.7 KB), so
// blocks/CU goes 3 -> 6-8 and the in-loop load latency hides via TLP.
// Epilogue: scalar gelu stores (R3-style; measured identical to fat stores).
__global__ __launch_bounds__(256) void k_inv(const uint* __restrict__ oyb,
    const uint* __restrict__ oxb, const ushort* __restrict__ VyCT,
    const ushort* __restrict__ VxCT, const float* __restrict__ b1,
    ushort* __restrict__ x2bf){
  __shared__ uint Bt[64*34];    // [n][k]  8.7 KB
  int bx = blockIdx.x;
  // swizzle: 6 blocks of one (bb,o) share an XCD (assumes round-robin bx%8->XCD)
  int c8 = bx & 7; int rr = bx >> 3; int slot = rr/6; int nt6 = rr - slot*6;
  int gid = slot*8 + c8;
  int bb = gid >> 5; int o = gid & 31;
  int n0 = nt6*64;
  int tid = threadIdx.x;
  int l = tid & 63, g = tid >> 6;
  int c15 = l & 15, q = l >> 4;
  const uint* oxp = oxb + (size_t)(bb*NW + o)*32*NSY;
  const uint* oyp = oyb + (size_t)(bb*NW + o)*32*NSX;
  #pragma unroll
  for (int i=0;i<8;i++){
    int idx = tid + i*256;          // < 2048
    int k = idx >> 6, n = idx & 63;
    int ng = n0 + n;
    Bt[n*34 + k] = (ng < NSX) ? oyp[(size_t)k*NSX + ng] : 0u;
  }
  __syncthreads();
  f32x4 acc[3][4];
  #pragma unroll
  for (int mt=0;mt<3;mt++)
    #pragma unroll
    for (int nt=0;nt<4;nt++) acc[mt][nt] = (f32x4){0.f,0.f,0.f,0.f};
  #pragma unroll
  for (int s=0;s<4;s++){
    bf16x8 bfr[4];
    #pragma unroll
    for (int nt=0;nt<4;nt++){
      if (s < 2){
        const uint* bp = &Bt[(nt*16 + c15)*34 + s*16 + q*4];
        U4 bu; uint2 lo = *(const uint2*)bp; uint2 hi = *(const uint2*)(bp+2);
        bu.u[0]=lo.x; bu.u[1]=lo.y; bu.u[2]=hi.x; bu.u[3]=hi.y;
        bfr[nt] = bu.v;
      } else {
        bfr[nt] = *(const bf16x8*)(VxCT + (size_t)(n0 + nt*16 + c15)*64 + (s-2)*32 + q*8);
      }
    }
    #pragma unroll
    for (int mt=0;mt<3;mt++){
      int mrow = g*48 + mt*16 + c15;
      bf16x8 afr;
      if (s < 2){
        afr = *(const bf16x8*)(VyCT + (size_t)mrow*64 + s*32 + q*8);
      } else {
        // direct global gather of ox[k][m]: rows >= NSY are clamped (their
        // MFMA output rows are masked at the store, C row m depends only on
        // A row m, so duplicated row-179 data is harmless)
        int mc = mrow < NSY ? mrow : (NSY-1);
        int k0 = (s-2)*16 + q*4;
        U4 au;
        #pragma unroll
        for (int j=0;j<4;j++)
          au.u[j] = oxp[(size_t)(k0+j)*NSY + mc];
        afr = au.v;
      }
      #pragma unroll
      for (int nt=0;nt<4;nt++)
        acc[mt][nt] = __builtin_amdgcn_mfma_f32_16x16x32_bf16(afr, bfr[nt], acc[mt][nt], 0,0,0);
    }
  }
  float bias = b1[o];
  ushort* xp = x2bf + (size_t)(bb*NW + o)*NPIX;
  #pragma unroll
  for (int mt=0;mt<3;mt++){
    #pragma unroll
    for (int nt=0;nt<4;nt++){
      int n = n0 + nt*16 + c15;
      if (n < NSX){
        #pragma unroll
        for (int r2=0;r2<4;r2++){
          int m = g*48 + mt*16 + q*4 + r2;
          if (m < NSY) xp[(size_t)m*NSX + n] = f2bf(gelu_f(acc[mt][nt][r2] + bias));
        }
      }
    }
  }
}

// ---------------- MFMA pointwise: hbf += (gelu?)(W2 @ x2g + b2) ----------------
// x2bf already holds gelu(x1+b1) (bf16, planar [bb][c][NPIX]).
// Block = 256 px of one bb; wave g: pixels g*64..g*64+63 (4 m-tiles x 2 n-tiles MFMA).
// Epilogue transposes through LDS so the hbf RMW is coalesced per-channel rows.
__global__ __launch_bounds__(256) void k_pw2(const ushort* __restrict__ x2bf,
    const ushort* __restrict__ w2b, const float* __restrict__ b2,
    uint* __restrict__ hbfu, int last, int b0, int nloc){
  const int HP = NPIX/2;            // 32400
  __shared__ uint Ot[32*132];       // [o][px2], stride 132 (16B-aligned rows, bank-spread)
  int blk = blockIdx.x;
  int bb = blk/254, bt = blk - bb*254;
  int pxb = bt*256;
  int tid = threadIdx.x;
  int g = tid >> 6, l = tid & 63;
  int c15 = l & 15, q = l >> 4;
  // B fragments: W2 bf16, [o][c]; col o = nt*16+c15, k = q*8+j
  bf16x8 bfr[2];
  #pragma unroll
  for (int nt=0; nt<2; nt++)
    bfr[nt] = *(const bf16x8*)(w2b + (size_t)(nt*16 + c15)*32 + q*8);
  // A fragments (gelu'd x2) + MFMA
  const ushort* xb = x2bf + ((size_t)bb*NW + q*8)*NPIX;
  f32x4 acc[4][2];
  #pragma unroll
  for (int mt=0;mt<4;mt++){
    U4 au; au.u[0]=0u; au.u[1]=0u; au.u[2]=0u; au.u[3]=0u;
    int pr = pxb + g*64 + mt*16 + c15;
    if (pr < NPIX){
      ushort v[8];
      #pragma unroll
      for (int j=0;j<8;j++) v[j] = xb[(size_t)j*NPIX + pr];
      #pragma unroll
      for (int i2=0;i2<4;i2++) au.u[i2] = (uint)v[2*i2] | ((uint)v[2*i2+1] << 16);
    }
    #pragma unroll
    for (int nt=0;nt<2;nt++){
      acc[mt][nt] = (f32x4){0.f,0.f,0.f,0.f};
      acc[mt][nt] = __builtin_amdgcn_mfma_f32_16x16x32_bf16(au.v, bfr[nt], acc[mt][nt], 0,0,0);
    }
  }
  // phase 1: bias + (gelu) -> LDS transpose [o][px2]
  #pragma unroll
  for (int nt=0;nt<2;nt++){
    int o = nt*16 + c15;
    float bias = b2[o];
    #pragma unroll
    for (int mt=0;mt<4;mt++){
      float v0 = acc[mt][nt][0] + bias;
      float v1 = acc[mt][nt][1] + bias;
      float v2 = acc[mt][nt][2] + bias;
      float v3 = acc[mt][nt][3] + bias;
      if (!last){ v0=gelu_f(v0); v1=gelu_f(v1); v2=gelu_f(v2); v3=gelu_f(v3); }
      int px2 = g*32 + mt*8 + q*2;            // (pixel within block)/2, even
      uint2 w2v; w2v.x = packbf2(v0,v1); w2v.y = packbf2(v2,v3);
      *(uint2*)(&Ot[o*132 + px2]) = w2v;
    }
  }
  __syncthreads();
  // phase 2: coalesced residual RMW on hbf; 8 threads per o-row, 16 uints each
  int o = tid >> 3, t8 = tid & 7;
  uint* hb = hbfu + ((size_t)((b0+bb)*NW + o))*HP + (pxb>>1) + t8*16;
  const uint* lrow = &Ot[o*132 + t8*16];
  int p2g0 = (pxb>>1) + t8*16;
  #pragma unroll
  for (int jj=0; jj<16; jj+=4){
    if (p2g0 + jj + 4 <= HP){
      uint4 hv = *(const uint4*)(hb + jj);
      uint4 av = *(const uint4*)(lrow + jj);
      uint4 r;
      r.x = addbf2(hv.x, av.x); r.y = addbf2(hv.y, av.y);
      r.z = addbf2(hv.z, av.z); r.w = addbf2(hv.w, av.w);
      *(uint4*)(hb + jj) = r;
    } else {
      #pragma unroll
      for (int t=0;t<4;t++){
        if (p2g0 + jj + t < HP){
          uint hv = hb[jj+t];
          hb[jj+t] = addbf2(hv, lrow[jj+t]);
        }
      }
    }
  }
}

// ---------------- MFMA fc1 + gelu + fc2 (reads bf16 hbf planar) ----------------
__global__ __launch_bounds__(256) void k_fc12m(const ushort* __restrict__ hbf,
    const ushort* __restrict__ f1Tbf, const float* __restrict__ f1b,
    const float* __restrict__ f2w, const float* __restrict__ f2b,
    float* __restrict__ out){
  int blk = blockIdx.x; int tid = threadIdx.x;
  int g = tid >> 6, lane = tid & 63;
  int c15 = lane & 15, q = lane >> 4;
  int pbase = blk*64 + g*16;
  int pglob = pbase + c15;
  int b = pglob/NPIX, r = pglob%NPIX;
  const ushort* hb = hbf + (size_t)b*NW*NPIX + r;
  U4 au;
  #pragma unroll
  for (int i=0;i<4;i++){
    uint v0 = hb[(size_t)(q*8 + 2*i)*NPIX];
    uint v1 = hb[(size_t)(q*8 + 2*i + 1)*NPIX];
    au.u[i] = v0 | (v1 << 16);
  }
  bf16x8 afr = au.v;
  f32x4 acc[8];
  #pragma unroll
  for (int t=0;t<8;t++) acc[t] = (f32x4){0.f,0.f,0.f,0.f};
  #pragma unroll
  for (int nt=0; nt<8; nt++){
    bf16x8 bfr = *(const bf16x8*)(f1Tbf + (size_t)(nt*16 + c15)*32 + q*8);
    acc[nt] = __builtin_amdgcn_mfma_f32_16x16x32_bf16(afr, bfr, acc[nt], 0,0,0);
  }
  float s[4] = {0.f,0.f,0.f,0.f};
  #pragma unroll
  for (int nt=0; nt<8; nt++){
    int j = nt*16 + c15;
    float bj = f1b[j], wj = f2w[j];
    #pragma unroll
    for (int r2=0;r2<4;r2++) s[r2] += gelu_f(acc[nt][r2] + bj) * wj;
  }
  #pragma unroll
  for (int msk=1; msk<16; msk<<=1){
    #pragma unroll
    for (int r2=0;r2<4;r2++) s[r2] += __shfl_xor(s[r2], msk, 64);
  }
  if (c15 == 0){
    float fb2 = f2b[0];
    float4 v = {s[0]+fb2, s[1]+fb2, s[2]+fb2, s[3]+fb2};
    *(float4*)(out + pbase + q*4) = v;
  }
}

extern "C" void kernel_launch(void* const* d_in, const int* in_sizes, int n_in,
                              void* d_out, int out_size, void* d_ws, size_t ws_size,
                              hipStream_t stream) {
  const float* x     = (const float*)d_in[0];
  const float* sx    = (const float*)d_in[1];
  const float* sy    = (const float*)d_in[2];
  const float* fc0_w = (const float*)d_in[3];
  const float* fc0_b = (const float*)d_in[4];
  const float* fw1   = (const float*)d_in[5];
  const float* fw2   = (const float*)d_in[6];
  const float* w1m   = (const float*)d_in[7];
  const float* b1    = (const float*)d_in[8];
  const float* w2m   = (const float*)d_in[9];
  const float* b2    = (const float*)d_in[10];
  const float* fc1_w = (const float*)d_in[11];
  const float* fc1_b = (const float*)d_in[12];
  const float* fc2_w = (const float*)d_in[13];
  const float* fc2_b = (const float*)d_in[14];
  float* out = (float*)d_out;

  char* wsb = (char*)d_ws;
  size_t off = 0;
  auto alloc = [&](size_t bytes)->char*{
    char* p = wsb + off;
    off = (off + bytes + 255) & ~(size_t)255;
    return p;
  };
  ushort* hbf   = (ushort*)alloc((size_t)NB*NW*NPIX*2);    // 66.4 MB (residual stream)
  ushort* Abfy  = (ushort*)alloc(64*192*2);
  ushort* Abfx  = (ushort*)alloc(64*384*2);
  ushort* VyCT  = (ushort*)alloc(192*64*2);
  ushort* VxCT  = (ushort*)alloc(384*64*2);
  ushort* f1Tbf = (ushort*)alloc(128*32*2);
  ushort* w2bf  = (ushort*)alloc(4096*2);
  float*  gx    = (float*)alloc(NSX*4);
  float*  gy    = (float*)alloc(NSY*4);
  float*  w1f   = (float*)alloc(262144*4);
  float*  w2f   = (float*)alloc(262144*4);
  const size_t fixedB = off;

  // per-batch: x2bf (4,147,200 B) ALIASES [fty | ftx | pad] (ft dead after k_mix)
  const size_t szX2  = (size_t)NW*NPIX*2;
  const size_t szFty = (size_t)NW*32*NSX*4;
  const size_t szFtx = (size_t)NW*32*NSY*4;
  const size_t szOy  = szFty, szOx = szFtx;
  const size_t perB  = szX2 + szOy + szOx;      // 6,359,040 B

  int NC = 16;
  while (NC > 1 && fixedB + (size_t)NC*perB + 4096 > ws_size) NC >>= 1;
  char* pb = wsb + fixedB;
  ushort* x2bf = (ushort*)pb;
  uint*   fty  = (uint*)pb;                               // aliases x2bf head
  uint*   ftx  = (uint*)(pb + (size_t)NC*szFty);          // aliases x2bf tail
  uint*   oy   = (uint*)(pb + (size_t)NC*szX2);
  uint*   ox   = (uint*)((char*)oy + (size_t)NC*szOy);

  k_prep<<<96, 256, 0, stream>>>(sx, sy, fc1_w, w2m, Abfy, Abfx, VyCT, VxCT,
                                 f1Tbf, w2bf, gx, gy);
  k_fold<<<1024, 256, 0, stream>>>(fw1, fw2, w1m, w1f, w2f);
  k_fc0<<<4050, 256, 0, stream>>>(x, gx, gy, fc0_w, fc0_b, hbf);

  for (int i=0;i<4;i++){
    for (int b0=0; b0<NB; b0+=NC){
      k_fwd<<<NC*288, 256, 0, stream>>>(hbf, Abfy, Abfx, fty, ftx, b0, NC*192);
      k_mix<<<NC*96, 192, 0, stream>>>(fty, ftx, w1f + (size_t)i*65536,
                                       w2f + (size_t)i*65536, oy, ox, NC*64);
      k_inv<<<NC*192, 256, 0, stream>>>(oy, ox, VyCT, VxCT, b1 + i*32, x2bf);
      k_pw2<<<NC*254, 256, 0, stream>>>((const ushort*)x2bf,
                                        w2bf + (size_t)i*1024,
                                        b2 + i*32, (uint*)hbf,
                                        (int)(i==3), b0, NC);
    }
  }

  k_fc12m<<<NPTS/64, 256, 0, stream>>>(hbf, f1Tbf, fc1_b, fc2_w, fc2_b, out);
}